// Round 10
// baseline (141.893 us; speedup 1.0000x reference)
//
#include <hip/hip_runtime.h>
#include <hip/hip_fp16.h>

// Problem constants (B,S,H,N_IN,N_PROC,R) = (4,1024,1024,64,16,128)
#define T_TOK 4096   // B*S tokens
#define H_DIM 1024
#define NIN   64
#define NP    16
#define R_DIM 128
#define S_DIM 1024
#define N1    (NP * R_DIM)   // 2048

typedef _Float16 half8  __attribute__((ext_vector_type(8)));
typedef _Float16 half4v __attribute__((ext_vector_type(4)));
typedef float    floatx16 __attribute__((ext_vector_type(16)));

typedef __attribute__((address_space(3))) unsigned char lds_u8_t;
typedef __attribute__((address_space(1))) unsigned char gbl_u8_t;

__device__ __forceinline__ void g2l16(const void* g, void* l) {
  __builtin_amdgcn_global_load_lds((const gbl_u8_t*)g, (lds_u8_t*)l, 16, 0, 0);
}

// ---------------- MFMA GEMM: C(BMxBN/block) = A(MxK) * BT(NxK)^T ------------
// BM=128. Double-buffered BK=64 K-loop, raw s_barrier + fine vmcnt: next
// tile's DMA stays in flight across the barrier. Grid >= 512 -> 2 blocks/CU.
// A LDS: 64 rows x 256B, row-pair packed (m,m+64 share row), 16-chunk XOR
// swizzle (R6/R8-verified 0 conflicts). B LDS (BN=64): 64 rows x 128B
// (64-HALF row stride — R9 bug was reading at 128-half stride), 8-chunk
// swizzle -> 8 lanes per 4-bank group = 2-way = free.
template <int BN, int GATE, int K, int N>
__global__ __launch_bounds__(256)
void gemm_kernel(const _Float16* __restrict__ A, const _Float16* __restrict__ BT,
                 const float* __restrict__ gv, void* __restrict__ Cv) {
  constexpr int NK = K / 64;
  constexpr int NJ = BN / 64;                  // 2 (GEMM1) or 1 (GEMM2)
  constexpr int BHALF = BN * 64;               // B halves per buffer
  constexpr int VW = 4 + BN / 32;              // DMA calls per wave per iter
  constexpr unsigned VM_PREF = 0xF70u | VW;    // vmcnt(VW)
  __shared__ __align__(16) _Float16 smem[2][64 * 128 + BHALF];

  const int tid = threadIdx.x, wave = tid >> 6, lane = tid & 63;
  const int bxi = blockIdx.x;
  const int m0 = blockIdx.y * 128, n0 = bxi * BN;
  const int wr = (wave >> 1) * 64, wc = (wave & 1) * (BN / 2);
  const int rl = lane >> 4, ql = lane & 15;    // A staging: 4 rows x 16 chunks
  const int rl8 = lane >> 3, ql8 = lane & 7;   // B staging (BN=64): 8 rows x 8
  const int r = lane & 31, kh = lane >> 5;

  auto stageA = [&](int k0, _Float16* dst) {
    #pragma unroll
    for (int c = 0; c < 4; ++c) {
      const int cc = wave * 4 + c;
      const int lrow = cc * 4 + rl;            // LDS row 0..63
      const int cl = ql ^ (lrow & 15);         // logical chunk
      const int row = lrow + ((cl >> 3) << 6); // row-pair unpack
      g2l16(A + (size_t)(m0 + row) * K + k0 + (cl & 7) * 8, dst + cc * 512);
    }
  };
  auto stageB = [&](int k0, _Float16* dst) {
    if constexpr (BN == 128) {
      #pragma unroll
      for (int c = 0; c < 4; ++c) {
        const int cc = wave * 4 + c;
        const int lrow = cc * 4 + rl;
        const int cl = ql ^ (lrow & 15);
        const int row = lrow + ((cl >> 3) << 6);
        g2l16(BT + (size_t)(n0 + row) * K + k0 + (cl & 7) * 8, dst + cc * 512);
      }
    } else {  // BN==64: 8 calls total, 2 per wave; 64 rows x 8 chunks (64-half rows)
      #pragma unroll
      for (int c = 0; c < 2; ++c) {
        const int cc = wave * 2 + c;
        const int row = cc * 8 + rl8;          // LDS row = global row 0..63
        const int cl = ql8 ^ (row & 7);
        g2l16(BT + (size_t)(n0 + row) * K + k0 + cl * 8, dst + cc * 512);
      }
    }
  };

  floatx16 acc[2][NJ];
  #pragma unroll
  for (int i = 0; i < 2; ++i)
    #pragma unroll
    for (int j = 0; j < NJ; ++j) acc[i][j] = (floatx16)0.f;

  _Float16 *cur = smem[0], *nxt = smem[1];
  stageA(0, cur);
  stageB(0, cur + 8192);

  #pragma unroll 2
  for (int k = 0; k < NK; ++k) {
    if (k + 1 < NK) {
      stageA((k + 1) * 64, nxt);
      stageB((k + 1) * 64, nxt + 8192);
      __builtin_amdgcn_s_waitcnt(VM_PREF);   // prev tile landed; VW in flight
    } else {
      __builtin_amdgcn_s_waitcnt(0xF70);     // vmcnt(0): final tile
    }
    __builtin_amdgcn_s_barrier();
    __builtin_amdgcn_sched_barrier(0);
    const _Float16* cB = cur + 8192;
    #pragma unroll
    for (int h = 0; h < 4; ++h) {
      const int pA = (2 * h + kh + ((wave >> 1) << 3)) ^ (r & 15);
      half8 af[2], bf[NJ];
      #pragma unroll
      for (int i = 0; i < 2; ++i)
        af[i] = *reinterpret_cast<const half8*>(&cur[(i * 32 + r) * 128 + pA * 8]);
      if constexpr (BN == 128) {
        const int pB = (2 * h + kh + ((wave & 1) << 3)) ^ (r & 15);
        #pragma unroll
        for (int j = 0; j < NJ; ++j)
          bf[j] = *reinterpret_cast<const half8*>(&cB[(j * 32 + r) * 128 + pB * 8]);
      } else {
        const int n = wc + r;                  // 0..63
        const int pB = (2 * h + kh) ^ (n & 7);
        bf[0] = *reinterpret_cast<const half8*>(&cB[n * 64 + pB * 8]);  // 64-half rows
      }
      #pragma unroll
      for (int i = 0; i < 2; ++i)
        #pragma unroll
        for (int j = 0; j < NJ; ++j)
          acc[i][j] = __builtin_amdgcn_mfma_f32_32x32x16_f16(af[i], bf[j], acc[i][j], 0, 0, 0);
    }
    __builtin_amdgcn_sched_barrier(0);
    __builtin_amdgcn_s_barrier();
    _Float16* t = cur; cur = nxt; nxt = t;
  }

  // 32x32 C/D layout: col = lane&31, row = (reg&3) + 8*(reg>>2) + 4*kh
  if (GATE) {
    _Float16* C = (_Float16*)Cv;   // BN==128 -> bxi == neuron n
    #pragma unroll
    for (int i = 0; i < 2; ++i)
      #pragma unroll
      for (int g4 = 0; g4 < 4; ++g4)
        #pragma unroll
        for (int rr = 0; rr < 4; ++rr) {
          const int rowL = wr + i * 32 + rr + 8 * g4 + 4 * kh;
          const float g = gv[(size_t)(m0 + rowL) * NP + bxi];
          #pragma unroll
          for (int j = 0; j < NJ; ++j)
            C[(size_t)(m0 + rowL) * N + n0 + wc + j * 32 + r] =
                (_Float16)(acc[i][j][g4 * 4 + rr] * g);
        }
  } else {
    float* C = (float*)Cv;
    #pragma unroll
    for (int i = 0; i < 2; ++i)
      #pragma unroll
      for (int g4 = 0; g4 < 4; ++g4)
        #pragma unroll
        for (int rr = 0; rr < 4; ++rr) {
          const int rowL = wr + i * 32 + rr + 8 * g4 + 4 * kh;
          #pragma unroll
          for (int j = 0; j < NJ; ++j)
            C[(size_t)(m0 + rowL) * N + n0 + wc + j * 32 + r] = acc[i][j][g4 * 4 + rr];
        }
  }
}

// ---------------- prep: gates + cast + 2 transposes, ONE dispatch -----------
__global__ __launch_bounds__(256)
void prep_kernel(const float* __restrict__ enr, const float* __restrict__ cw,
                 const float* __restrict__ cb, const float* __restrict__ inter,
                 const float* __restrict__ dproj, const float* __restrict__ uproj,
                 float* __restrict__ gates, _Float16* __restrict__ Xh,
                 _Float16* __restrict__ BT1, _Float16* __restrict__ UT) {
  __shared__ __align__(16) char smem[25664];
  const int tid = threadIdx.x;
  const int bx = blockIdx.x, nb = gridDim.x;
  {
    const float4* src = (const float4*)inter;
    half4v* dst = (half4v*)Xh;
    for (int i = bx * 256 + tid; i < T_TOK * H_DIM / 4; i += nb * 256) {
      float4 v = src[i];
      half4v o;
      o[0] = (_Float16)v.x; o[1] = (_Float16)v.y; o[2] = (_Float16)v.z; o[3] = (_Float16)v.w;
      dst[i] = o;
    }
  }
  if (bx < 256) {
    float (*sw)[321] = (float (*)[321])smem;
    float (*se)[NIN] = (float (*)[NIN])(smem + 20544);
    const int t0 = bx * 16;
    const int b = t0 >> 10, s0 = t0 & 1023;
    for (int i = tid; i < NP * 320; i += 256) sw[i / 320][i % 320] = cw[i];
    for (int i = tid; i < 20 * NIN; i += 256) {
      int rr = i >> 6, c = i & 63, s = s0 + rr - 2;
      se[rr][c] = (s >= 0 && s < S_DIM) ? enr[((size_t)b * S_DIM + s) * NIN + c] : 0.f;
    }
    __syncthreads();
    const int lt = tid >> 4, n = tid & 15;
    float acc = cb[n];
    #pragma unroll
    for (int dh = 0; dh < 5; ++dh) {
      const float* wrow = &sw[n][dh * 64];
      const float* erow = se[lt + dh];
      #pragma unroll
      for (int j = 0; j < NIN; ++j) acc += erow[j] * wrow[j];
    }
    gates[(size_t)(t0 + lt) * NP + n] = 1.f / (1.f + expf(-acc));
    __syncthreads();
  }
  for (int u = bx; u < 4096; u += nb) {
    const float* src; _Float16* dst; int rows, cols, bxt, byt;
    if (u < 2048) {
      int n = u >> 7, rem = u & 127;
      src = dproj + (size_t)n * H_DIM * R_DIM;
      dst = BT1 + (size_t)n * R_DIM * H_DIM;
      rows = H_DIM; cols = R_DIM; bxt = rem & 3; byt = rem >> 2;
    } else {
      int u2 = u - 2048;
      src = uproj; dst = UT; rows = N1; cols = H_DIM;
      bxt = u2 & 31; byt = u2 >> 5;
    }
    float (*tile)[33] = (float (*)[33])smem;
    const int c0 = bxt * 32, r0 = byt * 32;
    const int tx = tid & 31, ty = tid >> 5;
    #pragma unroll
    for (int k = 0; k < 32; k += 8)
      tile[ty + k][tx] = src[(size_t)(r0 + ty + k) * cols + c0 + tx];
    __syncthreads();
    #pragma unroll
    for (int k = 0; k < 32; k += 8)
      dst[(size_t)(c0 + ty + k) * rows + r0 + tx] = (_Float16)tile[tx][ty + k];
    __syncthreads();
  }
}

extern "C" void kernel_launch(void* const* d_in, const int* in_sizes, int n_in,
                              void* d_out, int out_size, void* d_ws, size_t ws_size,
                              hipStream_t stream) {
  const float* inter = (const float*)d_in[0];
  const float* enr   = (const float*)d_in[1];
  const float* convw = (const float*)d_in[2];
  const float* convb = (const float*)d_in[3];
  const float* dproj = (const float*)d_in[4];
  const float* uproj = (const float*)d_in[5];
  float* out   = (float*)d_out;
  float* gates = out + (size_t)T_TOK * H_DIM;

  _Float16* Xh  = (_Float16*)d_ws;
  _Float16* BT1 = Xh  + (size_t)T_TOK * H_DIM;
  _Float16* UT  = BT1 + (size_t)N1 * H_DIM;
  _Float16* Dsc = UT  + (size_t)H_DIM * N1;

  prep_kernel<<<8448, 256, 0, stream>>>(enr, convw, convb, inter, dproj, uproj,
                                        gates, Xh, BT1, UT);
  // GEMM1: 128x128 tiles, grid 16x32 = 512 = 2 blocks/CU
  gemm_kernel<128, 1, H_DIM, N1>
      <<<dim3(N1 / 128, T_TOK / 128), 256, 0, stream>>>(Xh, BT1, gates, (void*)Dsc);
  // GEMM2: 128x64 tiles, grid 16x32 = 512 = 2 blocks/CU
  gemm_kernel<64, 0, N1, H_DIM>
      <<<dim3(H_DIM / 64, T_TOK / 128), 256, 0, stream>>>(Dsc, UT, nullptr, (void*)out);
}

// Round 11
// 135.551 us; speedup vs baseline: 1.0468x; 1.0468x over previous
//
#include <hip/hip_runtime.h>
#include <hip/hip_fp16.h>

// Problem constants (B,S,H,N_IN,N_PROC,R) = (4,1024,1024,64,16,128)
#define T_TOK 4096   // B*S tokens
#define H_DIM 1024
#define NIN   64
#define NP    16
#define R_DIM 128
#define S_DIM 1024
#define N1    (NP * R_DIM)   // 2048

typedef _Float16 half8  __attribute__((ext_vector_type(8)));
typedef _Float16 half4v __attribute__((ext_vector_type(4)));
typedef float    floatx16 __attribute__((ext_vector_type(16)));

typedef __attribute__((address_space(3))) unsigned char lds_u8_t;
typedef __attribute__((address_space(1))) unsigned char gbl_u8_t;

__device__ __forceinline__ void g2l16(const void* g, void* l) {
  __builtin_amdgcn_global_load_lds((const gbl_u8_t*)g, (lds_u8_t*)l, 16, 0, 0);
}

// ---------------- MFMA GEMM: C(128x128/block) = A(MxK) * BT(NxK)^T ----------
// R8-proven config (best total 138.1): BM=BN=128, double-buffered BK=64,
// raw s_barrier + vmcnt(8) so next tile's DMA crosses the barrier in flight.
// A/B LDS: 64 rows x 256B, row-pair packed (m,m+64 share row), 16-chunk XOR
// swizzle (verified 0 bank conflicts). Waves 2x2, wave tile 64x64.
// R11 new: XCD-aware swizzle — 1-D grid, xcd=id&7, 4 consecutive by-slabs per
// XCD so each XCD L2 holds 4 x (128 rows x K) A-slabs (1-2 MB) with 8-16x
// reuse as L2 hits (linear dispatch pulled ALL of A into every XCD L2).
template <int GATE, int K, int N>
__global__ __launch_bounds__(256)
void gemm_kernel(const _Float16* __restrict__ A, const _Float16* __restrict__ BT,
                 const float* __restrict__ gv, void* __restrict__ Cv) {
  constexpr int NK = K / 64;
  constexpr int GX = N / 128;                  // tiles along N (16 or 8)
  __shared__ __align__(16) _Float16 smem[4][64 * 128];  // A0 A1 B0 B1

  const int tid = threadIdx.x, wave = tid >> 6, lane = tid & 63;
  const int id = blockIdx.x;
  const int xcd = id & 7, s = id >> 3;
  const int byi = s / GX + 4 * xcd;            // 4 by-slabs per XCD
  const int bxi = s % GX;
  const int m0 = byi * 128, n0 = bxi * 128;
  const int wr = (wave >> 1) * 64, wc = (wave & 1) * 64;
  const int rl = lane >> 4, ql = lane & 15;    // staging: 4 rows x 16 chunks
  const int r = lane & 31, kh = lane >> 5;

  auto stage = [&](const _Float16* __restrict__ base, int off0, int k0,
                   _Float16* dst) {
    #pragma unroll
    for (int c = 0; c < 4; ++c) {
      const int cc = wave * 4 + c;             // call id 0..15
      const int lrow = cc * 4 + rl;            // LDS row 0..63
      const int cl = ql ^ (lrow & 15);         // logical chunk this lane fetches
      const int row = lrow + ((cl >> 3) << 6); // row-pair unpack
      g2l16(base + (size_t)(off0 + row) * K + k0 + (cl & 7) * 8, dst + cc * 512);
    }
  };

  floatx16 acc[2][2];
  #pragma unroll
  for (int i = 0; i < 2; ++i)
    #pragma unroll
    for (int j = 0; j < 2; ++j) acc[i][j] = (floatx16)0.f;

  _Float16 *cA = smem[0], *nA = smem[1], *cB = smem[2], *nB = smem[3];
  stage(A, m0, 0, cA);
  stage(BT, n0, 0, cB);

  #pragma unroll 2
  for (int k = 0; k < NK; ++k) {
    if (k + 1 < NK) {
      stage(A, m0, (k + 1) * 64, nA);
      stage(BT, n0, (k + 1) * 64, nB);
      __builtin_amdgcn_s_waitcnt(0xF78);   // vmcnt(8): prev tile landed
    } else {
      __builtin_amdgcn_s_waitcnt(0xF70);   // vmcnt(0): final tile
    }
    __builtin_amdgcn_s_barrier();
    __builtin_amdgcn_sched_barrier(0);
    #pragma unroll
    for (int h = 0; h < 4; ++h) {
      const int pA = (2 * h + kh + ((wave >> 1) << 3)) ^ (r & 15);
      const int pB = (2 * h + kh + ((wave & 1) << 3)) ^ (r & 15);
      half8 af[2], bf[2];
      #pragma unroll
      for (int i = 0; i < 2; ++i)
        af[i] = *reinterpret_cast<const half8*>(&cA[(i * 32 + r) * 128 + pA * 8]);
      #pragma unroll
      for (int j = 0; j < 2; ++j)
        bf[j] = *reinterpret_cast<const half8*>(&cB[(j * 32 + r) * 128 + pB * 8]);
      #pragma unroll
      for (int i = 0; i < 2; ++i)
        #pragma unroll
        for (int j = 0; j < 2; ++j)
          acc[i][j] = __builtin_amdgcn_mfma_f32_32x32x16_f16(af[i], bf[j], acc[i][j], 0, 0, 0);
    }
    __builtin_amdgcn_sched_barrier(0);
    __builtin_amdgcn_s_barrier();          // reads done; next iter may overwrite
    _Float16* t;
    t = cA; cA = nA; nA = t;
    t = cB; cB = nB; nB = t;
  }

  // 32x32 C/D layout: col = lane&31, row = (reg&3) + 8*(reg>>2) + 4*kh
  if (GATE) {
    _Float16* C = (_Float16*)Cv;   // BN==128 -> bxi == neuron n
    #pragma unroll
    for (int i = 0; i < 2; ++i)
      #pragma unroll
      for (int g4 = 0; g4 < 4; ++g4)
        #pragma unroll
        for (int rr = 0; rr < 4; ++rr) {
          const int rowL = wr + i * 32 + rr + 8 * g4 + 4 * kh;
          const float g = gv[(size_t)(m0 + rowL) * NP + bxi];  // L1-hot
          #pragma unroll
          for (int j = 0; j < 2; ++j)
            C[(size_t)(m0 + rowL) * N + n0 + wc + j * 32 + r] =
                (_Float16)(acc[i][j][g4 * 4 + rr] * g);
        }
  } else {
    float* C = (float*)Cv;
    #pragma unroll
    for (int i = 0; i < 2; ++i)
      #pragma unroll
      for (int g4 = 0; g4 < 4; ++g4)
        #pragma unroll
        for (int rr = 0; rr < 4; ++rr) {
          const int rowL = wr + i * 32 + rr + 8 * g4 + 4 * kh;
          #pragma unroll
          for (int j = 0; j < 2; ++j)
            C[(size_t)(m0 + rowL) * N + n0 + wc + j * 32 + r] = acc[i][j][g4 * 4 + rr];
        }
  }
}

// ---------------- prep: gates + cast + 2 transposes, ONE dispatch -----------
__global__ __launch_bounds__(256)
void prep_kernel(const float* __restrict__ enr, const float* __restrict__ cw,
                 const float* __restrict__ cb, const float* __restrict__ inter,
                 const float* __restrict__ dproj, const float* __restrict__ uproj,
                 float* __restrict__ gates, _Float16* __restrict__ Xh,
                 _Float16* __restrict__ BT1, _Float16* __restrict__ UT) {
  __shared__ __align__(16) char smem[25664];
  const int tid = threadIdx.x;
  const int bx = blockIdx.x, nb = gridDim.x;
  {
    const float4* src = (const float4*)inter;
    half4v* dst = (half4v*)Xh;
    for (int i = bx * 256 + tid; i < T_TOK * H_DIM / 4; i += nb * 256) {
      float4 v = src[i];
      half4v o;
      o[0] = (_Float16)v.x; o[1] = (_Float16)v.y; o[2] = (_Float16)v.z; o[3] = (_Float16)v.w;
      dst[i] = o;
    }
  }
  if (bx < 256) {
    float (*sw)[321] = (float (*)[321])smem;
    float (*se)[NIN] = (float (*)[NIN])(smem + 20544);
    const int t0 = bx * 16;
    const int b = t0 >> 10, s0 = t0 & 1023;
    for (int i = tid; i < NP * 320; i += 256) sw[i / 320][i % 320] = cw[i];
    for (int i = tid; i < 20 * NIN; i += 256) {
      int rr = i >> 6, c = i & 63, s = s0 + rr - 2;
      se[rr][c] = (s >= 0 && s < S_DIM) ? enr[((size_t)b * S_DIM + s) * NIN + c] : 0.f;
    }
    __syncthreads();
    const int lt = tid >> 4, n = tid & 15;
    float acc = cb[n];
    #pragma unroll
    for (int dh = 0; dh < 5; ++dh) {
      const float* wrow = &sw[n][dh * 64];
      const float* erow = se[lt + dh];
      #pragma unroll
      for (int j = 0; j < NIN; ++j) acc += erow[j] * wrow[j];
    }
    gates[(size_t)(t0 + lt) * NP + n] = 1.f / (1.f + expf(-acc));
    __syncthreads();
  }
  for (int u = bx; u < 4096; u += nb) {
    const float* src; _Float16* dst; int rows, cols, bxt, byt;
    if (u < 2048) {
      int n = u >> 7, rem = u & 127;
      src = dproj + (size_t)n * H_DIM * R_DIM;
      dst = BT1 + (size_t)n * R_DIM * H_DIM;
      rows = H_DIM; cols = R_DIM; bxt = rem & 3; byt = rem >> 2;
    } else {
      int u2 = u - 2048;
      src = uproj; dst = UT; rows = N1; cols = H_DIM;
      bxt = u2 & 31; byt = u2 >> 5;
    }
    float (*tile)[33] = (float (*)[33])smem;
    const int c0 = bxt * 32, r0 = byt * 32;
    const int tx = tid & 31, ty = tid >> 5;
    #pragma unroll
    for (int k = 0; k < 32; k += 8)
      tile[ty + k][tx] = src[(size_t)(r0 + ty + k) * cols + c0 + tx];
    __syncthreads();
    #pragma unroll
    for (int k = 0; k < 32; k += 8)
      dst[(size_t)(c0 + ty + k) * rows + r0 + tx] = (_Float16)tile[tx][ty + k];
    __syncthreads();
  }
}

extern "C" void kernel_launch(void* const* d_in, const int* in_sizes, int n_in,
                              void* d_out, int out_size, void* d_ws, size_t ws_size,
                              hipStream_t stream) {
  const float* inter = (const float*)d_in[0];
  const float* enr   = (const float*)d_in[1];
  const float* convw = (const float*)d_in[2];
  const float* convb = (const float*)d_in[3];
  const float* dproj = (const float*)d_in[4];
  const float* uproj = (const float*)d_in[5];
  float* out   = (float*)d_out;
  float* gates = out + (size_t)T_TOK * H_DIM;

  _Float16* Xh  = (_Float16*)d_ws;
  _Float16* BT1 = Xh  + (size_t)T_TOK * H_DIM;
  _Float16* UT  = BT1 + (size_t)N1 * H_DIM;
  _Float16* Dsc = UT  + (size_t)H_DIM * N1;

  prep_kernel<<<8448, 256, 0, stream>>>(enr, convw, convb, inter, dproj, uproj,
                                        gates, Xh, BT1, UT);
  // GEMM1: 128x128 tiles, 1-D grid 512, XCD-swizzled
  gemm_kernel<1, H_DIM, N1>
      <<<(N1 / 128) * (T_TOK / 128), 256, 0, stream>>>(Xh, BT1, gates, (void*)Dsc);
  // GEMM2: 128x128 tiles, 1-D grid 256, XCD-swizzled (R8 config)
  gemm_kernel<0, N1, H_DIM>
      <<<(H_DIM / 128) * (T_TOK / 128), 256, 0, stream>>>(Dsc, UT, nullptr, (void*)out);
}